// Round 1
// baseline (370.997 us; speedup 1.0000x reference)
//
#include <hip/hip_runtime.h>
#include <math.h>

#define NTOK   65536
#define MDIM   1024
#define NE     64     // experts
#define TT     64     // tokens per block
#define MC     64     // M chunk
#define XPAD   68     // 68 floats = 272 B, 16B-aligned rows
#define WPAD   65

// Output layout (flat f32, concatenated in reference return order):
//   gates  [NTOK*NE]
//   H      [NTOK*NE]
//   topk_idx [NTOK*2]  (written as float(idx))
//   noise_scale [NTOK*NE]
//   logits [NTOK*NE]

__global__ __launch_bounds__(256, 2) void noisy_topk_gate_kernel(
    const float* __restrict__ x,      // [NTOK][MDIM]
    const float* __restrict__ noise,  // [NTOK][NE]
    const float* __restrict__ Wg_w,   // [NE][MDIM]
    const float* __restrict__ Wg_b,   // [NE]
    const float* __restrict__ Wn_w,   // [NE][MDIM]
    const float* __restrict__ Wn_b,   // [NE]
    float* __restrict__ out_gates,
    float* __restrict__ out_H,
    float* __restrict__ out_idx,
    float* __restrict__ out_ns,
    float* __restrict__ out_logits)
{
    __shared__ float xs[TT][XPAD];
    __shared__ float wgs[MC][WPAD];
    __shared__ float wns[MC][WPAD];

    const int tid  = threadIdx.x;
    const int lane = tid & 63;        // expert index
    const int wave = tid >> 6;        // 0..3, owns tokens [wave*16, wave*16+16)
    const int tok0 = blockIdx.x * TT;

    float accg[16], accn[16];
#pragma unroll
    for (int j = 0; j < 16; ++j) { accg[j] = 0.f; accn[j] = 0.f; }

    for (int mc = 0; mc < MDIM; mc += MC) {
        if (mc != 0) __syncthreads();   // protect LDS from previous compute

        // ---- stage x tile: 64 tokens x 64 m, as float4 (1024 float4 / 256 thr = 4 each)
#pragma unroll
        for (int k = 0; k < 4; ++k) {
            const int f   = tid + k * 256;
            const int tok = f >> 4;          // 16 float4 per row
            const int mq  = f & 15;
            const float4 v = *reinterpret_cast<const float4*>(
                &x[(size_t)(tok0 + tok) * MDIM + mc + mq * 4]);
            *reinterpret_cast<float4*>(&xs[tok][mq * 4]) = v;
        }
        // ---- stage W chunks transposed: wgs[m][e], wns[m][e]
#pragma unroll
        for (int k = 0; k < 4; ++k) {
            const int f  = tid + k * 256;
            const int e  = f >> 4;
            const int mq = f & 15;
            const float4 vg = *reinterpret_cast<const float4*>(
                &Wg_w[(size_t)e * MDIM + mc + mq * 4]);
            const float4 vn = *reinterpret_cast<const float4*>(
                &Wn_w[(size_t)e * MDIM + mc + mq * 4]);
            wgs[mq * 4 + 0][e] = vg.x; wgs[mq * 4 + 1][e] = vg.y;
            wgs[mq * 4 + 2][e] = vg.z; wgs[mq * 4 + 3][e] = vg.w;
            wns[mq * 4 + 0][e] = vn.x; wns[mq * 4 + 1][e] = vn.y;
            wns[mq * 4 + 2][e] = vn.z; wns[mq * 4 + 3][e] = vn.w;
        }
        __syncthreads();

        // ---- compute: lane = expert, 16 tokens per wave
#pragma unroll 4
        for (int m = 0; m < MC; m += 4) {
            float wgv[4], wnv[4];
#pragma unroll
            for (int i = 0; i < 4; ++i) {
                wgv[i] = wgs[m + i][lane];
                wnv[i] = wns[m + i][lane];
            }
#pragma unroll
            for (int j = 0; j < 16; ++j) {
                const float4 xv = *reinterpret_cast<const float4*>(&xs[wave * 16 + j][m]);
                float ag = accg[j], an = accn[j];
                ag = fmaf(xv.x, wgv[0], ag);
                ag = fmaf(xv.y, wgv[1], ag);
                ag = fmaf(xv.z, wgv[2], ag);
                ag = fmaf(xv.w, wgv[3], ag);
                an = fmaf(xv.x, wnv[0], an);
                an = fmaf(xv.y, wnv[1], an);
                an = fmaf(xv.z, wnv[2], an);
                an = fmaf(xv.w, wnv[3], an);
                accg[j] = ag; accn[j] = an;
            }
        }
    }

    // ---- epilogue
    const float bg = Wg_b[lane];
    const float bn = Wn_b[lane];

#pragma unroll
    for (int j = 0; j < 16; ++j) {
        const int tok = tok0 + wave * 16 + j;
        const float lg = accg[j] + bg;
        const float nl = accn[j] + bn;
        // softplus, stable: max(x,0) + log1p(exp(-|x|))
        const float ns = fmaxf(nl, 0.f) + log1pf(expf(-fabsf(nl)));
        const float nz = noise[(size_t)tok * NE + lane];
        const float h  = fmaf(nz, ns, lg);

        out_logits[(size_t)tok * NE + lane] = lg;
        out_ns[(size_t)tok * NE + lane]     = ns;
        out_H[(size_t)tok * NE + lane]      = h;

        // top-1 (value, lowest index on ties)
        float v1 = h; int i1 = lane;
#pragma unroll
        for (int off = 32; off >= 1; off >>= 1) {
            const float ov = __shfl_xor(v1, off, 64);
            const int   oi = __shfl_xor(i1, off, 64);
            if (ov > v1 || (ov == v1 && oi < i1)) { v1 = ov; i1 = oi; }
        }
        // top-2: exclude argmax lane by index
        float v2 = (lane == i1) ? -INFINITY : h; int i2 = lane;
#pragma unroll
        for (int off = 32; off >= 1; off >>= 1) {
            const float ov = __shfl_xor(v2, off, 64);
            const int   oi = __shfl_xor(i2, off, 64);
            if (ov > v2 || (ov == v2 && oi < i2)) { v2 = ov; i2 = oi; }
        }

        // softmax over [v1, v2] (v1 >= v2)
        const float e2  = expf(v2 - v1);
        const float inv = 1.f / (1.f + e2);
        const float p1  = inv;
        const float p2  = e2 * inv;

        out_gates[(size_t)tok * NE + lane] =
            (lane == i1) ? p1 : ((lane == i2) ? p2 : 0.f);

        if (lane == 0) {
            out_idx[(size_t)tok * 2 + 0] = (float)i1;
            out_idx[(size_t)tok * 2 + 1] = (float)i2;
        }
    }
}

extern "C" void kernel_launch(void* const* d_in, const int* in_sizes, int n_in,
                              void* d_out, int out_size, void* d_ws, size_t ws_size,
                              hipStream_t stream) {
    const float* x     = (const float*)d_in[0];
    const float* noise = (const float*)d_in[1];
    const float* Wg_w  = (const float*)d_in[2];
    const float* Wg_b  = (const float*)d_in[3];
    const float* Wn_w  = (const float*)d_in[4];
    const float* Wn_b  = (const float*)d_in[5];

    float* out = (float*)d_out;
    float* out_gates  = out;
    float* out_H      = out + (size_t)NTOK * NE;
    float* out_idx    = out + (size_t)2 * NTOK * NE;
    float* out_ns     = out + (size_t)2 * NTOK * NE + (size_t)NTOK * 2;
    float* out_logits = out + (size_t)3 * NTOK * NE + (size_t)NTOK * 2;

    dim3 grid(NTOK / TT);   // 1024 blocks
    dim3 block(256);
    noisy_topk_gate_kernel<<<grid, block, 0, stream>>>(
        x, noise, Wg_w, Wg_b, Wn_w, Wn_b,
        out_gates, out_H, out_idx, out_ns, out_logits);
}